// Round 6
// baseline (233.312 us; speedup 1.0000x reference)
//
#include <hip/hip_runtime.h>
#include <hip/hip_bf16.h>
#include <cstddef>

// 3-layer tanh RNN (B=8192, T=80, D=32, H=64), fused, MFMA, systolic layer pipeline
// + RAW BARRIERS (lgkmcnt-only) so global x prefetches stay in flight across ticks.
//
// Block = 192 thr = 3 waves; wave wv computes LAYER wv at local time lt = tau - wv.
// One raw s_barrier per tick (82 ticks). __syncthreads would emit
// s_waitcnt vmcnt(0) before s_barrier, draining the x prefetch every tick
// (~80 x ~1000 cyc — the measured ~90us invariant across R3/R4/R5). Here:
//   asm-clobber; s_waitcnt(0xC07F)  // lgkmcnt(0) only — LDS handoff correct
//   s_barrier; asm-clobber
// x is prefetched DEPTH-2 (registers), so its vmcnt wait lands at use, two full
// ticks after issue.
//
// MFMA 16x16x32 bf16, A = weights (VGPR-resident), B = activations:
//   A-frag: lane holds A[m=lane&15][k=8*(lane>>4)+i]
//   B-frag: lane holds B[k=8*(lane>>4)+i][n=lane&15]
//   C/D:    lane holds D[row=4*(lane>>4)+r][col=lane&15]      (verified R2-R5)
// h exchange: hb[layer][t&1][batch][j] (stride 72 shorts). Own-recurrence
// transpose read back pre-barrier (same-wave DS order => RAW safe).

typedef __attribute__((ext_vector_type(8))) short s16x8;
typedef __attribute__((ext_vector_type(4))) short s16x4;
typedef __attribute__((ext_vector_type(4))) float fx4;

#define MFMA16(A, B, C) __builtin_amdgcn_mfma_f32_16x16x32_bf16((A), (B), (C), 0, 0, 0)

// lgkmcnt(0), vmcnt=63 (no wait), expcnt=7 (no wait) -> 0xC07F on gfx9-class.
#define BAR_LGKM()                                  \
  do {                                              \
    __asm__ __volatile__("" ::: "memory");          \
    __builtin_amdgcn_s_waitcnt(0xC07F);             \
    __builtin_amdgcn_s_barrier();                   \
    __asm__ __volatile__("" ::: "memory");          \
  } while (0)

#if __has_builtin(__builtin_amdgcn_exp2f)
#define EXP2F(x) __builtin_amdgcn_exp2f(x)
#else
#define EXP2F(x) exp2f(x)
#endif
#if __has_builtin(__builtin_amdgcn_rcpf)
#define RCPF(x) __builtin_amdgcn_rcpf(x)
#else
#define RCPF(x) (1.0f / (x))
#endif

static constexpr float K2LOG2E = 2.8853900817779268f;  // 2*log2(e)

__device__ __forceinline__ short f2bf(float f) {  // RNE float->bf16 (weights, one-time)
  union { float f; unsigned u; } v; v.f = f;
  unsigned r = v.u + 0x7FFFu + ((v.u >> 16) & 1u);
  return (short)(r >> 16);
}
__device__ __forceinline__ unsigned pk2bf(float a, float b) {  // v_cvt_pk_bf16_f32
  float2 t; t.x = a; t.y = b;
  union { __hip_bfloat162 h; unsigned u; } c;
  c.h = __float22bfloat162_rn(t);
  return c.u;
}

__device__ __forceinline__ s16x8 wfragA(const float* W, int ncols, int row, int col0) {
  const float* p = W + row * ncols + col0;
  s16x8 r;
#pragma unroll
  for (int i = 0; i < 8; ++i) r[i] = f2bf(p[i]);
  return r;
}

__global__ __launch_bounds__(192, 2) void rnn3_pipe_rb(
    const float* __restrict__ x,
    const float* __restrict__ Wih0, const float* __restrict__ Whh0,
    const float* __restrict__ bih0, const float* __restrict__ bhh0,
    const float* __restrict__ Wih1, const float* __restrict__ Whh1,
    const float* __restrict__ bih1, const float* __restrict__ bhh1,
    const float* __restrict__ Wih2, const float* __restrict__ Whh2,
    const float* __restrict__ bih2, const float* __restrict__ bhh2,
    const float* __restrict__ Wfc, const float* __restrict__ bfc,
    float* __restrict__ out)
{
  __shared__ __align__(16) short hb[3][2][16][72];  // [layer][t&1][batch][j], 13824 B

  const int tid = threadIdx.x;
  const int wv  = __builtin_amdgcn_readfirstlane(tid >> 6);  // 0..2 == layer
  const int ln  = tid & 63;
  const int q   = ln >> 4;
  const int m15 = ln & 15;
  const int bbase = (int)blockIdx.x * 16;

  // ---------- this wave's layer parameters ----------
  const float* Wih = (wv == 0) ? Wih0 : (wv == 1) ? Wih1 : Wih2;
  const float* Whh = (wv == 0) ? Whh0 : (wv == 1) ? Whh1 : Whh2;
  const float* bi  = (wv == 0) ? bih0 : (wv == 1) ? bih1 : bih2;
  const float* bh  = (wv == 0) ? bhh0 : (wv == 1) ? bhh1 : bhh2;
  const int kin = (wv == 0) ? 32 : 64;   // input width (x vs h)

  // ---------- weight A-fragments, all 4 j-tiles of this layer (VGPR-resident) ----
  s16x8 wi0[4], wi1[4], wh0[4], wh1[4];
  const s16x8 z8 = {0, 0, 0, 0, 0, 0, 0, 0};
#pragma unroll
  for (int tile = 0; tile < 4; ++tile) {
    const int row = 16 * tile + m15;
    wi0[tile] = wfragA(Wih, kin, row, 8 * q);
    wi1[tile] = wv ? wfragA(Wih, 64, row, 32 + 8 * q) : z8;   // layer 0: K=32 only
    wh0[tile] = wfragA(Whh, 64, row, 8 * q);
    wh1[tile] = wfragA(Whh, 64, row, 32 + 8 * q);
  }

  // ---------- biases pre-scaled by 2*log2(e); lane's j = 16*tile + 4*q + r ------
  float bsc[4][4];
#pragma unroll
  for (int tile = 0; tile < 4; ++tile)
#pragma unroll
    for (int r = 0; r < 4; ++r) {
      const int j = 16 * tile + 4 * q + r;
      bsc[tile][r] = (bi[j] + bh[j]) * K2LOG2E;
    }

  const fx4 z4 = {0.f, 0.f, 0.f, 0.f};
  s16x8 r0 = z8, r1 = z8;          // own recurrent state h_wv(t-1), B-layout

  // wave 0's x source, depth-2 register prefetch: slot lt&1 holds x(lt).
  const float* xr = x + (size_t)(bbase + m15) * (80 * 32) + 8 * q;
  fx4 xb0[2], xb1[2];
  if (wv == 0) {
    xb0[0] = *(const fx4*)(xr);            xb1[0] = *(const fx4*)(xr + 4);
    xb0[1] = *(const fx4*)(xr + 32);       xb1[1] = *(const fx4*)(xr + 32 + 4);
  }

  float hk[4][4];                  // tanh outputs of the last computed tick (FC use)

  for (int tau = 0; tau < 82; ++tau) {
    const int lt = tau - wv;                 // this wave's time step
    if (0 <= lt && lt < 80) {                // wave-uniform guard
      const int p = lt & 1;
      // ---- input B-frags ----
      s16x8 in0, in1;
      if (wv) {
        const short* up = &hb[wv - 1][p][m15][8 * q];   // h_{wv-1}(lt), upstream
        in0 = *(const s16x8*)(up);
        in1 = *(const s16x8*)(up + 32);
      } else {
        const fx4 xc0 = xb0[p], xc1 = xb1[p];           // loaded 2 ticks ago
        union { unsigned u[4]; s16x8 v; } xp;
        xp.u[0] = pk2bf(xc0[0], xc0[1]); xp.u[1] = pk2bf(xc0[2], xc0[3]);
        xp.u[2] = pk2bf(xc1[0], xc1[1]); xp.u[3] = pk2bf(xc1[2], xc1[3]);
        in0 = xp.v; in1 = z8;
        const int tn = (lt < 78) ? lt + 2 : 79;         // refill slot with x(lt+2)
        xb0[p] = *(const fx4*)(xr + tn * 32);
        xb1[p] = *(const fx4*)(xr + tn * 32 + 4);
      }
      // ---- MFMA: Whh*rec first (registers ready) to hide the upstream ds_read ----
      fx4 acc[4];
#pragma unroll
      for (int tile = 0; tile < 4; ++tile) acc[tile] = MFMA16(wh0[tile], r0, z4);
#pragma unroll
      for (int tile = 0; tile < 4; ++tile) acc[tile] = MFMA16(wh1[tile], r1, acc[tile]);
#pragma unroll
      for (int tile = 0; tile < 4; ++tile) acc[tile] = MFMA16(wi0[tile], in0, acc[tile]);
      if (wv) {
#pragma unroll
        for (int tile = 0; tile < 4; ++tile) acc[tile] = MFMA16(wi1[tile], in1, acc[tile]);
      }
      // ---- tanh + pack + store h_wv(lt) ----
      short* wb = &hb[wv][p][m15][4 * q];
#pragma unroll
      for (int tile = 0; tile < 4; ++tile) {
        float h[4];
#pragma unroll
        for (int r = 0; r < 4; ++r) {
          float e = EXP2F(__builtin_fmaf(acc[tile][r], K2LOG2E, bsc[tile][r]));
          h[r] = __builtin_fmaf(-2.f, RCPF(e + 1.f), 1.f);
          hk[tile][r] = h[r];
        }
        union { unsigned u[2]; s16x4 v; } pk;
        pk.u[0] = pk2bf(h[0], h[1]);
        pk.u[1] = pk2bf(h[2], h[3]);
        *(s16x4*)(wb + 16 * tile) = pk.v;
      }
      // ---- own-recurrence transpose readback (pre-barrier; same-wave RAW safe) ----
      const short* ow = &hb[wv][p][m15][8 * q];
      r0 = *(const s16x8*)(ow);
      r1 = *(const s16x8*)(ow + 32);
    }
    BAR_LGKM();                              // raw barrier: lgkm drained, vmem NOT
  }

  // ---------- FC head: wave 2's last tick produced h2(79) in hk ----------
  if (wv == 2) {
    float s = 0.f;
#pragma unroll
    for (int tile = 0; tile < 4; ++tile)
#pragma unroll
      for (int r = 0; r < 4; ++r)
        s += hk[tile][r] * Wfc[16 * tile + 4 * q + r];
    s += __shfl_xor(s, 16, 64);
    s += __shfl_xor(s, 32, 64);
    if (ln < 16) out[bbase + ln] = s + bfc[0];
  }
}

extern "C" void kernel_launch(void* const* d_in, const int* in_sizes, int n_in,
                              void* d_out, int out_size, void* d_ws, size_t ws_size,
                              hipStream_t stream) {
  const float* x    = (const float*)d_in[0];
  const float* Wih0 = (const float*)d_in[1];
  const float* Whh0 = (const float*)d_in[2];
  const float* bih0 = (const float*)d_in[3];
  const float* bhh0 = (const float*)d_in[4];
  const float* Wih1 = (const float*)d_in[5];
  const float* Whh1 = (const float*)d_in[6];
  const float* bih1 = (const float*)d_in[7];
  const float* bhh1 = (const float*)d_in[8];
  const float* Wih2 = (const float*)d_in[9];
  const float* Whh2 = (const float*)d_in[10];
  const float* bih2 = (const float*)d_in[11];
  const float* bhh2 = (const float*)d_in[12];
  const float* Wfc  = (const float*)d_in[13];
  const float* bfc  = (const float*)d_in[14];

  // 512 blocks x 192 thr (3 waves = 3 pipelined layers), 16 batch rows per block.
  rnn3_pipe_rb<<<dim3(512), dim3(192), 0, stream>>>(
      x, Wih0, Whh0, bih0, bhh0, Wih1, Whh1, bih1, bhh1,
      Wih2, Whh2, bih2, bhh2, Wfc, bfc, (float*)d_out);
}